// Round 4
// baseline (236.650 us; speedup 1.0000x reference)
//
#include <hip/hip_runtime.h>
#include <math.h>

// DTW 2048x2048, squared-diff cost, out = sqrt(DTW[2047][2047]).
//
// Skew-1 wave pipeline, NW=4 waves (256 thr, 1 wave/SIMD), 8 LOGICAL
// strips of 256 rows; wave w runs strips w (role A) and w+4 (role B).
// Lane l owns 4 rows of each strip (strip rows 4l..4l+3); at wave-step t
// it computes column j = t - l for both roles.
//
// WHY two roles per lane (round-4 change): R0/R2 (NW=4, R=8) = 144cy/step,
// pure chain (dpp + 8x(min3+fma) = 17 dep ops, 1 wave/SIMD fully exposed).
// R3 (NW=8, R=4) showed hardware TLP does NOT hide it: two identical
// waves/SIMD run in lockstep convoy (stalls coincide), 131cy/step.
// Here the overlap is INSTRUCTION-level within one wave: two independent
// 9-op chains (roles touch disjoint strips, coupled only via the LDS ring
// with >=96-step slack), statement-interleaved so the SIMD pipelines them.
// Expected per-step ~ max(chain 9 ops, issue ~38 VALU) ~ half of 144.
// (Round-1's version of this failed because inline-asm min3 blinded the
// scheduler and serialized the chains; this is pure builtins -- round 2
// proved fminf(fminf()) fuses to v_min3_f32 natively.)
//
// Per 32-step block, per role: TWO coalesced ds_read_b32 (y[tau0+lane],
// ring[tau0+lane]); per step, v_readlane(blk, s) (compile-time s) yields
// wave-uniform y[tau0+s] / ring[tau0+s], injected into DPP wave_shr:1
// conveyors (yc: lane l holds y[t-l]; u: lane l holds lane l-1's row-3
// value, lane 0 gets the ring injection = row above the strip).
//
// min3 via unsigned-int bitcast min (all DP values non-negative; IEEE
// ordering == unsigned ordering): fuses to v_min3_u32.
//
// Guard-free: INFV=1e30 absorbs adds (1e30 + d^2 == 1e30 in fp32), so
// ramp junk stays exactly INFV; OOB ring writes (j<0 ramp-in, j>=2048
// ramp-out) land in pad regions. Inactive roles simply skip their body
// (their v-state stays INFV until activation). Output is stored at the
// unique step (role B, tauB==2080, s==30, w=3, lane 63) where j==2047,
// row = strip7 local row 255 = global 2047.
//
// Ring: 9 rows (strip s reads ring[s], writes ring[s+1]), unwrapped cols,
// PAD=64 left pad, cols -64..2111. Producer strip s-1 (lane 63) writes
// col c at its step c+63; consumer block tau0 readlane-uses cols
// <= tau0+31; DSKEW=96 + barrier every 32 steps gives the producer
// completed steps < tau0+96 > tau0+31+63. CSTEP=32/DSKEW=96 (vs 64/128)
// trims ramp: GTOT 2784 equivalent steps vs 3008.

#define NLEN   2048
#define NSTRIP 8
#define NW     4
#define CSTEP  32
#define DSKEW  96
#define PAD    64
#define RROW   (PAD + NLEN + 2 * CSTEP)                 // 2176: cols -64..2111
#define TAUMAX (NLEN + CSTEP)                           // 2080
#define GTOT   (TAUMAX + CSTEP + (NSTRIP - 1) * DSKEW)  // 2784
#define INFV   1e30f

__device__ __forceinline__ float dpp_shr1(float v, float inj) {
    int r = __builtin_amdgcn_update_dpp(
        __builtin_bit_cast(int, inj), __builtin_bit_cast(int, v),
        0x138 /*wave_shr:1*/, 0xF, 0xF, false /*lane0 keeps old=inj*/);
    return __builtin_bit_cast(float, r);
}
__device__ __forceinline__ float rdlane(float v, int l) {
    return __builtin_bit_cast(float,
        __builtin_amdgcn_readlane(__builtin_bit_cast(int, v), l));
}
// 3-input min on non-negative floats via unsigned bit-pattern compare;
// umin+umin fuses to a single v_min3_u32.
__device__ __forceinline__ float min3f(float a, float b, float c) {
    unsigned ia = __builtin_bit_cast(unsigned, a);
    unsigned ib = __builtin_bit_cast(unsigned, b);
    unsigned ic = __builtin_bit_cast(unsigned, c);
    unsigned m  = __builtin_elementwise_min(
                      __builtin_elementwise_min(ia, ib), ic);
    return __builtin_bit_cast(float, m);
}

__global__ __launch_bounds__(256, 1) void dtw_kernel(const float* __restrict__ X,
                                                     const float* __restrict__ Y,
                                                     float* __restrict__ out) {
    __shared__ __align__(16) float yS[NLEN];
    __shared__ float ring[(NSTRIP + 1) * RROW];

    const int tid  = threadIdx.x;
    const int w    = tid >> 6;
    const int lane = tid & 63;

    {
        const float4* Y4 = (const float4*)Y;
        float4* y4 = (float4*)yS;
        y4[tid]       = Y4[tid];
        y4[tid + 256] = Y4[tid + 256];
    }
    // Entire ring INFV: virtual row -1, pads, and unwritten tails.
    for (int k = tid; k < (NSTRIP + 1) * RROW; k += 256) ring[k] = INFV;
    __syncthreads();

    // Role A: strip w, global rows tid*4..+3.  Role B: strip w+4, +1024.
    float xA0, xA1, xA2, xA3, xB0, xB1, xB2, xB3;
    {
        const float4 a = *(const float4*)&X[tid * 4];
        xA0 = a.x; xA1 = a.y; xA2 = a.z; xA3 = a.w;
        const float4 b = *(const float4*)&X[1024 + tid * 4];
        xB0 = b.x; xB1 = b.y; xB2 = b.z; xB3 = b.w;
    }

    float vA0 = INFV, vA1 = INFV, vA2 = INFV, vA3 = INFV;
    float vB0 = INFV, vB1 = INFV, vB2 = INFV, vB3 = INFV;
    float upA = (tid == 0) ? 0.0f : INFV;   // DTW[-1][-1]=0 seed (strip 0)
    float upB = INFV;
    float ycA = 0.0f, ycB = 0.0f;           // y DPP conveyors

    const float* rrA = ring + w * RROW + PAD;
    float*       rwA = ring + (w + 1) * RROW + PAD;
    const float* rrB = ring + (w + 4) * RROW + PAD;
    float*       rwB = ring + (w + 5) * RROW + PAD;

    for (int gb = 0; gb < GTOT; gb += CSTEP) {
        const int tauA = gb - w * DSKEW;
        const int tauB = gb - (w + 4) * DSKEW;
        const bool actA = (tauA >= 0) & (tauA <= TAUMAX);
        const bool actB = (tauB >= 0) & (tauB <= TAUMAX);

        if (actA & actB) {
            int yiA = tauA + lane; if (yiA >= NLEN) yiA = NLEN - 1;
            int yiB = tauB + lane; if (yiB >= NLEN) yiB = NLEN - 1;
            const float ybA = yS[yiA];
            const float ybB = yS[yiB];
            const float rbA = rrA[tauA + lane];
            const float rbB = rrB[tauB + lane];
            float* wpA = rwA + (tauA - lane);
            float* wpB = rwB + (tauB - lane);

            #pragma unroll
            for (int s = 0; s < CSTEP; ++s) {
                const float yuA = rdlane(ybA, s);
                const float yuB = rdlane(ybB, s);
                const float ruA = rdlane(rbA, s);
                const float ruB = rdlane(rbB, s);
                ycA = dpp_shr1(ycA, yuA);
                ycB = dpp_shr1(ycB, yuB);
                const float uA = dpp_shr1(vA3, ruA);
                const float uB = dpp_shr1(vB3, ruB);
                float dA0 = xA0 - ycA;                 float dB0 = xB0 - ycB;
                float nA0 = fmaf(dA0, dA0, min3f(vA0, upA, uA));
                float nB0 = fmaf(dB0, dB0, min3f(vB0, upB, uB));
                float dA1 = xA1 - ycA;                 float dB1 = xB1 - ycB;
                float nA1 = fmaf(dA1, dA1, min3f(vA1, vA0, nA0));
                float nB1 = fmaf(dB1, dB1, min3f(vB1, vB0, nB0));
                float dA2 = xA2 - ycA;                 float dB2 = xB2 - ycB;
                float nA2 = fmaf(dA2, dA2, min3f(vA2, vA1, nA1));
                float nB2 = fmaf(dB2, dB2, min3f(vB2, vB1, nB1));
                float dA3 = xA3 - ycA;                 float dB3 = xB3 - ycB;
                float nA3 = fmaf(dA3, dA3, min3f(vA3, vA2, nA2));
                float nB3 = fmaf(dB3, dB3, min3f(vB3, vB2, nB2));
                wpA[s] = nA3;
                wpB[s] = nB3;
                upA = uA; upB = uB;
                vA0 = nA0; vA1 = nA1; vA2 = nA2; vA3 = nA3;
                vB0 = nB0; vB1 = nB1; vB2 = nB2; vB3 = nB3;
            }
        } else if (actA) {
            int yiA = tauA + lane; if (yiA >= NLEN) yiA = NLEN - 1;
            const float ybA = yS[yiA];
            const float rbA = rrA[tauA + lane];
            float* wpA = rwA + (tauA - lane);

            #pragma unroll
            for (int s = 0; s < CSTEP; ++s) {
                const float yuA = rdlane(ybA, s);
                const float ruA = rdlane(rbA, s);
                ycA = dpp_shr1(ycA, yuA);
                const float uA = dpp_shr1(vA3, ruA);
                float dA0 = xA0 - ycA; float nA0 = fmaf(dA0, dA0, min3f(vA0, upA, uA));
                float dA1 = xA1 - ycA; float nA1 = fmaf(dA1, dA1, min3f(vA1, vA0, nA0));
                float dA2 = xA2 - ycA; float nA2 = fmaf(dA2, dA2, min3f(vA2, vA1, nA1));
                float dA3 = xA3 - ycA; float nA3 = fmaf(dA3, dA3, min3f(vA3, vA2, nA2));
                wpA[s] = nA3;
                upA = uA;
                vA0 = nA0; vA1 = nA1; vA2 = nA2; vA3 = nA3;
            }
        } else if (actB) {
            int yiB = tauB + lane; if (yiB >= NLEN) yiB = NLEN - 1;
            const float ybB = yS[yiB];
            const float rbB = rrB[tauB + lane];
            float* wpB = rwB + (tauB - lane);
            const bool isout = (tauB == TAUMAX) & (w == NW - 1) & (lane == 63);

            #pragma unroll
            for (int s = 0; s < CSTEP; ++s) {
                const float yuB = rdlane(ybB, s);
                const float ruB = rdlane(rbB, s);
                ycB = dpp_shr1(ycB, yuB);
                const float uB = dpp_shr1(vB3, ruB);
                float dB0 = xB0 - ycB; float nB0 = fmaf(dB0, dB0, min3f(vB0, upB, uB));
                float dB1 = xB1 - ycB; float nB1 = fmaf(dB1, dB1, min3f(vB1, vB0, nB0));
                float dB2 = xB2 - ycB; float nB2 = fmaf(dB2, dB2, min3f(vB2, vB1, nB1));
                float dB3 = xB3 - ycB; float nB3 = fmaf(dB3, dB3, min3f(vB3, vB2, nB2));
                wpB[s] = nB3;
                upB = uB;
                vB0 = nB0; vB1 = nB1; vB2 = nB2; vB3 = nB3;
                if (s == 30 && isout) out[0] = sqrtf(nB3);  // j == 2047
            }
        }
        __syncthreads();
    }
}

extern "C" void kernel_launch(void* const* d_in, const int* in_sizes, int n_in,
                              void* d_out, int out_size, void* d_ws, size_t ws_size,
                              hipStream_t stream) {
    const float* x = (const float*)d_in[0];
    const float* y = (const float*)d_in[1];
    (void)in_sizes; (void)n_in; (void)out_size; (void)d_ws; (void)ws_size;
    dtw_kernel<<<1, 256, 0, stream>>>(x, y, (float*)d_out);
}